// Round 3
// baseline (766.915 us; speedup 1.0000x reference)
//
#include <hip/hip_runtime.h>

typedef float f4 __attribute__((ext_vector_type(4)));

#define Gn 4
#define Bn 2
#define Tn 32
#define Cn 128
#define CG 32      // channels per head-group
#define Hn 64
#define Wn 64
#define HC 16
#define WC 16

#define QT 16      // q-tile per block (q split across 2 blocks)
#define APAD 20    // LDS row stride in floats (16B-aligned rows, spreads banks)

// block = (g, b, h, whalf, qtile); 256 threads; thread tile = 4q x 4c x 4w (float4 over w)
// LDS 25.6 KB -> 6 blocks/CU (24 waves/CU). qtile pair placed 8 apart in dispatch
// index so both land on the same XCD and share x through that XCD's L2.
__global__ __launch_bounds__(256, 6)
void temporal_agg_kernel(const float* __restrict__ x,
                         const float* __restrict__ attn,
                         float* __restrict__ out) {
    const int bid   = blockIdx.x;
    // pair members (qt=0/1) differ by 8 in dispatch index -> same XCD under
    // round-robin mod-8 XCD assignment, launched back-to-back.
    const int qt    = (bid >> 3) & 1;
    const int pair  = ((bid >> 4) << 3) | (bid & 7);   // [0, 1024)
    const int whalf = pair & 1;
    const int h     = (pair >> 1) & 63;
    const int b     = (pair >> 7) & 1;
    const int g     = pair >> 8;

    const int tid = threadIdx.x;

    // half-pixel h interpolation: src = 0.25*h - 0.375
    const float chf = 0.25f * (float)h - 0.375f;
    const float h0f = floorf(chf);
    const float fh  = chf - h0f;
    int h0 = (int)h0f;
    int h1 = h0 + 1;
    h0 = min(max(h0, 0), HC - 1);
    h1 = min(max(h1, 0), HC - 1);

    // Ah[k][j][q]: h-interpolated coarse attn, j = coarse-w col (10 cols incl. halo),
    // q fastest (QT=16, row stride 20 floats -> 16B-aligned rows, 4-cy b128 reads)
    __shared__ float Ah[Tn][10][APAD];

    // ---- phase 1: global -> LDS, h-lerp, transpose to q-fast ----
    const int wcb = whalf * 8 - 1;  // coarse col of j=0 (may be -1 -> clamped dup)
    const float* abase = attn + (size_t)(g * Bn + b) * (Tn * Tn * HC * WC)
                              + (size_t)(qt * QT) * (Tn * HC * WC);
    #pragma unroll 8
    for (int i = 0; i < 32; ++i) {
        int idx = tid + 256 * i;      // [0, 8192)
        int wc = idx & 15;
        int k  = (idx >> 4) & 31;
        int q  = idx >> 9;            // [0, 16)
        const float* p = abase + (size_t)(q * Tn + k) * (HC * WC);
        float v0 = p[h0 * WC + wc];
        float v1 = p[h1 * WC + wc];
        float ah = v0 + fh * (v1 - v0);
        int j = wc - wcb;
        if (j >= 0 && j < 10) Ah[k][j][q] = ah;
        if (whalf == 0 && wc == 0)  Ah[k][0][q] = ah;  // clamp(-1) -> col 0
        if (whalf == 1 && wc == 15) Ah[k][9][q] = ah;  // clamp(16) -> col 15
    }
    __syncthreads();

    // ---- phase 2: per-pixel temporal matmul (single pass, all 32 c) ----
    const int qslot = tid & 3;         // 4 * 4 = 16 q in this q-tile
    const int wl    = (tid >> 2) & 7;  // 8 * 4 = 32 fine w in this half
    const int cslot = tid >> 5;        // 8 * 4 = 32 c
    const int q0    = qslot * 4;
    const int wfine = whalf * 32 + wl * 4;
    const int off_hw = h * Wn + wfine;

    f4 acc[4][4];
    #pragma unroll
    for (int qq = 0; qq < 4; ++qq)
        #pragma unroll
        for (int cc = 0; cc < 4; ++cc)
            acc[qq][cc] = (f4)0.0f;

    const int cbase = g * CG + cslot * 4;
    const float* xb = x + (size_t)b * (Tn * Cn * Hn * Wn)
                        + (size_t)cbase * (Hn * Wn) + off_hw;

    #pragma unroll 2
    for (int k = 0; k < Tn; ++k) {
        // A taps: coarse cols wl, wl+1, wl+2 cover fine w = 4*wl + {0..3}
        f4 t0 = *(const f4*)&Ah[k][wl    ][q0];
        f4 t1 = *(const f4*)&Ah[k][wl + 1][q0];
        f4 t2 = *(const f4*)&Ah[k][wl + 2][q0];

        f4 xv[4];
        const float* xk = xb + (size_t)k * (Cn * Hn * Wn);
        #pragma unroll
        for (int cc = 0; cc < 4; ++cc)
            xv[cc] = *(const f4*)(xk + cc * (Hn * Wn));

        #pragma unroll
        for (int qq = 0; qq < 4; ++qq) {
            f4 a;
            a.x = 0.375f * t0[qq] + 0.625f * t1[qq];
            a.y = 0.125f * t0[qq] + 0.875f * t1[qq];
            a.z = 0.875f * t1[qq] + 0.125f * t2[qq];
            a.w = 0.625f * t1[qq] + 0.375f * t2[qq];
            #pragma unroll
            for (int cc = 0; cc < 4; ++cc)
                acc[qq][cc] += a * xv[cc];
        }
    }

    #pragma unroll
    for (int qq = 0; qq < 4; ++qq) {
        const int q = qt * QT + q0 + qq;
        float* ob = out + ((size_t)(b * Tn + q) * Cn + cbase) * (Hn * Wn) + off_hw;
        #pragma unroll
        for (int cc = 0; cc < 4; ++cc)
            __builtin_nontemporal_store(acc[qq][cc], (f4*)(ob + cc * (Hn * Wn)));
    }
}

extern "C" void kernel_launch(void* const* d_in, const int* in_sizes, int n_in,
                              void* d_out, int out_size, void* d_ws, size_t ws_size,
                              hipStream_t stream) {
    const float* x    = (const float*)d_in[0];
    const float* attn = (const float*)d_in[1];
    float* out        = (float*)d_out;
    temporal_agg_kernel<<<dim3(Gn * Bn * Hn * 2 * 2), dim3(256), 0, stream>>>(x, attn, out);
}

// Round 4
// 760.850 us; speedup vs baseline: 1.0080x; 1.0080x over previous
//
#include <hip/hip_runtime.h>

typedef float f4 __attribute__((ext_vector_type(4)));

#define Gn 4
#define Bn 2
#define Tn 32
#define Cn 128
#define CG 32      // channels per head-group
#define Hn 64
#define Wn 64
#define HC 16
#define WC 16

#define QT 16      // q-tile per block (q split across 2 blocks)
#define APAD 20    // LDS row stride in floats (16B-aligned rows, spreads banks)

// block = (g, b, h, whalf, qtile); 256 threads; thread tile = 4q x 4c x 4w (float4 over w)
// LDS 25.6 KB -> 6 blocks/CU (24 waves/CU). qtile pair placed 8 apart in dispatch
// index so both land on the same XCD and share x through that XCD's L2.
// NOTE: plain stores only — nontemporal 16B/lane stores caused 7x HBM write
// amplification on gfx950 (bypassed L2 write-combining; measured r3).
__global__ __launch_bounds__(256, 6)
void temporal_agg_kernel(const float* __restrict__ x,
                         const float* __restrict__ attn,
                         float* __restrict__ out) {
    const int bid   = blockIdx.x;
    // pair members (qt=0/1) differ by 8 in dispatch index -> same XCD under
    // round-robin mod-8 XCD assignment, launched back-to-back.
    const int qt    = (bid >> 3) & 1;
    const int pair  = ((bid >> 4) << 3) | (bid & 7);   // [0, 1024)
    const int whalf = pair & 1;
    const int h     = (pair >> 1) & 63;
    const int b     = (pair >> 7) & 1;
    const int g     = pair >> 8;

    const int tid = threadIdx.x;

    // half-pixel h interpolation: src = 0.25*h - 0.375
    const float chf = 0.25f * (float)h - 0.375f;
    const float h0f = floorf(chf);
    const float fh  = chf - h0f;
    int h0 = (int)h0f;
    int h1 = h0 + 1;
    h0 = min(max(h0, 0), HC - 1);
    h1 = min(max(h1, 0), HC - 1);

    // Ah[k][j][q]: h-interpolated coarse attn, j = coarse-w col (10 cols incl. halo),
    // q fastest (QT=16, row stride 20 floats -> 16B-aligned rows, 4-cy b128 reads)
    __shared__ float Ah[Tn][10][APAD];

    // ---- phase 1: global -> LDS, h-lerp, transpose to q-fast ----
    const int wcb = whalf * 8 - 1;  // coarse col of j=0 (may be -1 -> clamped dup)
    const float* abase = attn + (size_t)(g * Bn + b) * (Tn * Tn * HC * WC)
                              + (size_t)(qt * QT) * (Tn * HC * WC);
    #pragma unroll 8
    for (int i = 0; i < 32; ++i) {
        int idx = tid + 256 * i;      // [0, 8192)
        int wc = idx & 15;
        int k  = (idx >> 4) & 31;
        int q  = idx >> 9;            // [0, 16)
        const float* p = abase + (size_t)(q * Tn + k) * (HC * WC);
        float v0 = p[h0 * WC + wc];
        float v1 = p[h1 * WC + wc];
        float ah = v0 + fh * (v1 - v0);
        int j = wc - wcb;
        if (j >= 0 && j < 10) Ah[k][j][q] = ah;
        if (whalf == 0 && wc == 0)  Ah[k][0][q] = ah;  // clamp(-1) -> col 0
        if (whalf == 1 && wc == 15) Ah[k][9][q] = ah;  // clamp(16) -> col 15
    }
    __syncthreads();

    // ---- phase 2: per-pixel temporal matmul (single pass, all 32 c) ----
    const int qslot = tid & 3;         // 4 * 4 = 16 q in this q-tile
    const int wl    = (tid >> 2) & 7;  // 8 * 4 = 32 fine w in this half
    const int cslot = tid >> 5;        // 8 * 4 = 32 c
    const int q0    = qslot * 4;
    const int wfine = whalf * 32 + wl * 4;
    const int off_hw = h * Wn + wfine;

    f4 acc[4][4];
    #pragma unroll
    for (int qq = 0; qq < 4; ++qq)
        #pragma unroll
        for (int cc = 0; cc < 4; ++cc)
            acc[qq][cc] = (f4)0.0f;

    const int cbase = g * CG + cslot * 4;
    const float* xb = x + (size_t)b * (Tn * Cn * Hn * Wn)
                        + (size_t)cbase * (Hn * Wn) + off_hw;

    #pragma unroll 2
    for (int k = 0; k < Tn; ++k) {
        // A taps: coarse cols wl, wl+1, wl+2 cover fine w = 4*wl + {0..3}
        f4 t0 = *(const f4*)&Ah[k][wl    ][q0];
        f4 t1 = *(const f4*)&Ah[k][wl + 1][q0];
        f4 t2 = *(const f4*)&Ah[k][wl + 2][q0];

        f4 xv[4];
        const float* xk = xb + (size_t)k * (Cn * Hn * Wn);
        #pragma unroll
        for (int cc = 0; cc < 4; ++cc)
            xv[cc] = *(const f4*)(xk + cc * (Hn * Wn));

        #pragma unroll
        for (int qq = 0; qq < 4; ++qq) {
            f4 a;
            a.x = 0.375f * t0[qq] + 0.625f * t1[qq];
            a.y = 0.125f * t0[qq] + 0.875f * t1[qq];
            a.z = 0.875f * t1[qq] + 0.125f * t2[qq];
            a.w = 0.625f * t1[qq] + 0.375f * t2[qq];
            #pragma unroll
            for (int cc = 0; cc < 4; ++cc)
                acc[qq][cc] += a * xv[cc];
        }
    }

    #pragma unroll
    for (int qq = 0; qq < 4; ++qq) {
        const int q = qt * QT + q0 + qq;
        float* ob = out + ((size_t)(b * Tn + q) * Cn + cbase) * (Hn * Wn) + off_hw;
        #pragma unroll
        for (int cc = 0; cc < 4; ++cc)
            *(f4*)(ob + cc * (Hn * Wn)) = acc[qq][cc];
    }
}

extern "C" void kernel_launch(void* const* d_in, const int* in_sizes, int n_in,
                              void* d_out, int out_size, void* d_ws, size_t ws_size,
                              hipStream_t stream) {
    const float* x    = (const float*)d_in[0];
    const float* attn = (const float*)d_in[1];
    float* out        = (float*)d_out;
    temporal_agg_kernel<<<dim3(Gn * Bn * Hn * 2 * 2), dim3(256), 0, stream>>>(x, attn, out);
}

// Round 5
// 322.386 us; speedup vs baseline: 2.3789x; 2.3601x over previous
//
#include <hip/hip_runtime.h>

typedef float f4 __attribute__((ext_vector_type(4)));

#define Gn 4
#define Bn 2
#define Tn 32
#define Cn 128
#define CG 32      // channels per head-group
#define Hn 64
#define Wn 64
#define HC 16
#define WC 16

#define QT 16      // q-tile per block (q split across 2 blocks)
#define APAD 20    // LDS row stride in floats (16B-aligned rows, spreads banks)

// block = (g, b, h, whalf, qtile); 256 threads; thread tile = 4q x 4c x 4w (float4 over w)
// LDS 25.6 KB -> 6 blocks/CU. qtile pair placed 8 apart in dispatch index so both
// land on the same XCD and share x through that XCD's L2.
// launch_bounds min-waves MUST stay <=4: (256,6) capped VGPRs at 85 and spilled
// the 64-float accumulator to scratch -> 7x HBM write amplification (measured
// r3/r4: VGPR 40, WRITE 928MB vs 131MB ideal). With budget 128 the code uses
// ~84 VGPRs naturally -> floor(512/84)=6 waves/SIMD anyway, no spill.
__global__ __launch_bounds__(256, 4)
void temporal_agg_kernel(const float* __restrict__ x,
                         const float* __restrict__ attn,
                         float* __restrict__ out) {
    const int bid   = blockIdx.x;
    // pair members (qt=0/1) differ by 8 in dispatch index -> same XCD under
    // round-robin mod-8 XCD assignment, launched back-to-back.
    const int qt    = (bid >> 3) & 1;
    const int pair  = ((bid >> 4) << 3) | (bid & 7);   // [0, 1024)
    const int whalf = pair & 1;
    const int h     = (pair >> 1) & 63;
    const int b     = (pair >> 7) & 1;
    const int g     = pair >> 8;

    const int tid = threadIdx.x;

    // half-pixel h interpolation: src = 0.25*h - 0.375
    const float chf = 0.25f * (float)h - 0.375f;
    const float h0f = floorf(chf);
    const float fh  = chf - h0f;
    int h0 = (int)h0f;
    int h1 = h0 + 1;
    h0 = min(max(h0, 0), HC - 1);
    h1 = min(max(h1, 0), HC - 1);

    // Ah[k][j][q]: h-interpolated coarse attn, j = coarse-w col (10 cols incl. halo),
    // q fastest (QT=16, row stride 20 floats -> 16B-aligned rows)
    __shared__ float Ah[Tn][10][APAD];

    // ---- phase 1: global -> LDS, h-lerp, transpose to q-fast ----
    const int wcb = whalf * 8 - 1;  // coarse col of j=0 (may be -1 -> clamped dup)
    const float* abase = attn + (size_t)(g * Bn + b) * (Tn * Tn * HC * WC)
                              + (size_t)(qt * QT) * (Tn * HC * WC);
    #pragma unroll 8
    for (int i = 0; i < 32; ++i) {
        int idx = tid + 256 * i;      // [0, 8192)
        int wc = idx & 15;
        int k  = (idx >> 4) & 31;
        int q  = idx >> 9;            // [0, 16)
        const float* p = abase + (size_t)(q * Tn + k) * (HC * WC);
        float v0 = p[h0 * WC + wc];
        float v1 = p[h1 * WC + wc];
        float ah = v0 + fh * (v1 - v0);
        int j = wc - wcb;
        if (j >= 0 && j < 10) Ah[k][j][q] = ah;
        if (whalf == 0 && wc == 0)  Ah[k][0][q] = ah;  // clamp(-1) -> col 0
        if (whalf == 1 && wc == 15) Ah[k][9][q] = ah;  // clamp(16) -> col 15
    }
    __syncthreads();

    // ---- phase 2: per-pixel temporal matmul (single pass, all 32 c) ----
    const int qslot = tid & 3;         // 4 * 4 = 16 q in this q-tile
    const int wl    = (tid >> 2) & 7;  // 8 * 4 = 32 fine w in this half
    const int cslot = tid >> 5;        // 8 * 4 = 32 c
    const int q0    = qslot * 4;
    const int wfine = whalf * 32 + wl * 4;
    const int off_hw = h * Wn + wfine;

    f4 acc[4][4];
    #pragma unroll
    for (int qq = 0; qq < 4; ++qq)
        #pragma unroll
        for (int cc = 0; cc < 4; ++cc)
            acc[qq][cc] = (f4)0.0f;

    const int cbase = g * CG + cslot * 4;
    const float* xb = x + (size_t)b * (Tn * Cn * Hn * Wn)
                        + (size_t)cbase * (Hn * Wn) + off_hw;

    #pragma unroll 2
    for (int k = 0; k < Tn; ++k) {
        // A taps: coarse cols wl, wl+1, wl+2 cover fine w = 4*wl + {0..3}
        f4 t0 = *(const f4*)&Ah[k][wl    ][q0];
        f4 t1 = *(const f4*)&Ah[k][wl + 1][q0];
        f4 t2 = *(const f4*)&Ah[k][wl + 2][q0];

        f4 xv[4];
        const float* xk = xb + (size_t)k * (Cn * Hn * Wn);
        #pragma unroll
        for (int cc = 0; cc < 4; ++cc)
            xv[cc] = *(const f4*)(xk + cc * (Hn * Wn));

        #pragma unroll
        for (int qq = 0; qq < 4; ++qq) {
            f4 a;
            a.x = 0.375f * t0[qq] + 0.625f * t1[qq];
            a.y = 0.125f * t0[qq] + 0.875f * t1[qq];
            a.z = 0.875f * t1[qq] + 0.125f * t2[qq];
            a.w = 0.625f * t1[qq] + 0.375f * t2[qq];
            #pragma unroll
            for (int cc = 0; cc < 4; ++cc)
                acc[qq][cc] += a * xv[cc];
        }
    }

    #pragma unroll
    for (int qq = 0; qq < 4; ++qq) {
        const int q = qt * QT + q0 + qq;
        float* ob = out + ((size_t)(b * Tn + q) * Cn + cbase) * (Hn * Wn) + off_hw;
        #pragma unroll
        for (int cc = 0; cc < 4; ++cc)
            *(f4*)(ob + cc * (Hn * Wn)) = acc[qq][cc];
    }
}

extern "C" void kernel_launch(void* const* d_in, const int* in_sizes, int n_in,
                              void* d_out, int out_size, void* d_ws, size_t ws_size,
                              hipStream_t stream) {
    const float* x    = (const float*)d_in[0];
    const float* attn = (const float*)d_in[1];
    float* out        = (float*)d_out;
    temporal_agg_kernel<<<dim3(Gn * Bn * Hn * 2 * 2), dim3(256), 0, stream>>>(x, attn, out);
}

// Round 6
// 296.731 us; speedup vs baseline: 2.5846x; 1.0865x over previous
//
#include <hip/hip_runtime.h>

typedef float f4 __attribute__((ext_vector_type(4)));
typedef const __attribute__((address_space(1))) void gas_t;
typedef __attribute__((address_space(3))) void las_t;

#define Gn 4
#define Bn 2
#define Tn 32
#define Cn 128
#define CG 32      // channels per head-group
#define Hn 64
#define Wn 64
#define HC 16
#define WC 16

#define QT 16      // q-tile per block (q split across 2 blocks)
#define APAD 20    // Ah row stride in floats
#define NSLOT 5    // x-staging slots: DEPTH in flight + 1 guard (WAR margin)
#define DEPTH 4    // k-slices prefetched ahead (vmcnt(DEPTH-1) in steady state)

// block = (g, b, h, whalf, qtile); 256 threads; thread tile = 4q x 4c x 4w.
// x is staged global->LDS via global_load_lds, 4 k-slices deep, wave-private
// (wave w stages channels 8w..8w+7 = exactly what its lanes consume) -> no
// barrier in the k-loop; per-wave counted vmcnt(3) only.
// Taps read as 4x ds_read_b32 with q strided (qsl+4i): bank = 20j+qsl+4i mod 32
// covers all 32 banks once -> conflict-free (b128 taps were structurally 4-way).
// launch_bounds(256,3): LDS 45.6KB caps at 3 blocks/CU anyway; give VGPRs room
// (r3/r4 lesson: tight caps spill acc -> 7x HBM write amplification).
__global__ __launch_bounds__(256, 3)
void temporal_agg_kernel(const float* __restrict__ x,
                         const float* __restrict__ attn,
                         float* __restrict__ out) {
    const int bid   = blockIdx.x;
    const int qt    = (bid >> 3) & 1;
    const int pair  = ((bid >> 4) << 3) | (bid & 7);   // [0, 1024)
    const int whalf = pair & 1;
    const int h     = (pair >> 1) & 63;
    const int b     = (pair >> 7) & 1;
    const int g     = pair >> 8;

    const int tid  = threadIdx.x;
    const int lane = tid & 63;
    const int wid  = tid >> 6;

    __shared__ float Ah[Tn][10][APAD];    // 25.6 KB
    __shared__ float Xs[NSLOT][CG][32];   // 20.0 KB

    // ---- x prefetch prologue: fire first DEPTH k-slices (no Ah dependency);
    // latency hides under phase 1. Wave w lane l writes Xs[s][8w + l/8][(l&7)*4]
    // (HW: wave-uniform LDS base + lane*16), matching per-lane global src.
    const int c_ld = 8 * wid + (lane >> 3);
    const float* xsrc = x + ((size_t)(b * Tn) * Cn + (g * CG + c_ld)) * (Hn * Wn)
                          + h * Wn + whalf * 32 + (lane & 7) * 4;

#define STAGE(k_, slot_) \
    __builtin_amdgcn_global_load_lds((gas_t*)(xsrc + (size_t)(k_) * (Cn * Hn * Wn)), \
                                     (las_t*)&Xs[slot_][8 * wid][0], 16, 0, 0)

    STAGE(0, 0); STAGE(1, 1); STAGE(2, 2); STAGE(3, 3);

    // half-pixel h interpolation: src = 0.25*h - 0.375
    const float chf = 0.25f * (float)h - 0.375f;
    const float h0f = floorf(chf);
    const float fh  = chf - h0f;
    int h0 = (int)h0f;
    int h1 = h0 + 1;
    h0 = min(max(h0, 0), HC - 1);
    h1 = min(max(h1, 0), HC - 1);

    // ---- phase 1: attn -> LDS, h-lerp, transpose to q-fast ----
    const int wcb = whalf * 8 - 1;  // coarse col of j=0 (may be -1 -> clamped dup)
    const float* abase = attn + (size_t)(g * Bn + b) * (Tn * Tn * HC * WC)
                              + (size_t)(qt * QT) * (Tn * HC * WC);
    #pragma unroll 8
    for (int i = 0; i < 32; ++i) {
        int idx = tid + 256 * i;      // [0, 8192)
        int wc = idx & 15;
        int k  = (idx >> 4) & 31;
        int q  = idx >> 9;            // [0, 16)
        const float* p = abase + (size_t)(q * Tn + k) * (HC * WC);
        float v0 = p[h0 * WC + wc];
        float v1 = p[h1 * WC + wc];
        float ah = v0 + fh * (v1 - v0);
        int j = wc - wcb;
        if (j >= 0 && j < 10) Ah[k][j][q] = ah;
        if (whalf == 0 && wc == 0)  Ah[k][0][q] = ah;  // clamp(-1) -> col 0
        if (whalf == 1 && wc == 15) Ah[k][9][q] = ah;  // clamp(16) -> col 15
    }
    __syncthreads();

    // ---- phase 2: per-pixel temporal matmul, software-pipelined x ----
    const int qsl   = tid & 3;         // q = qsl + 4*qq (strided -> b32 taps)
    const int wl    = (tid >> 2) & 7;  // 8 * 4 = 32 fine w in this half
    const int cslot = tid >> 5;        // local channel group, 4 c each
    const int wfine = whalf * 32 + wl * 4;
    const int off_hw = h * Wn + wfine;

    f4 acc[4][4];
    #pragma unroll
    for (int qq = 0; qq < 4; ++qq)
        #pragma unroll
        for (int cc = 0; cc < 4; ++cc)
            acc[qq][cc] = (f4)0.0f;

    auto body = [&](int k, int cur) {
        float t0[4], t1[4], t2[4];
        #pragma unroll
        for (int i = 0; i < 4; ++i) {
            t0[i] = Ah[k][wl    ][qsl + 4 * i];
            t1[i] = Ah[k][wl + 1][qsl + 4 * i];
            t2[i] = Ah[k][wl + 2][qsl + 4 * i];
        }
        f4 xv[4];
        #pragma unroll
        for (int cc = 0; cc < 4; ++cc)
            xv[cc] = *(const f4*)&Xs[cur][cslot * 4 + cc][wl * 4];

        #pragma unroll
        for (int qq = 0; qq < 4; ++qq) {
            f4 a;
            a.x = 0.375f * t0[qq] + 0.625f * t1[qq];
            a.y = 0.125f * t0[qq] + 0.875f * t1[qq];
            a.z = 0.875f * t1[qq] + 0.125f * t2[qq];
            a.w = 0.625f * t1[qq] + 0.375f * t2[qq];
            #pragma unroll
            for (int cc = 0; cc < 4; ++cc)
                acc[qq][cc] += a * xv[cc];
        }
    };

    int cur = 0;
    for (int k = 0; k < Tn - DEPTH; ++k) {
        // counted wait: oldest (slot for k) complete, DEPTH-1 stay in flight
        asm volatile("s_waitcnt vmcnt(3)" ::: "memory");
        body(k, cur);
        // drain LDS reads before overwriting slot (cur-1) = read last iter;
        // 5-slot ring gives one extra iteration of WAR margin on top.
        asm volatile("s_waitcnt lgkmcnt(0)" ::: "memory");
        const int ws = (cur == 0) ? (NSLOT - 1) : (cur - 1);  // (k+DEPTH) % NSLOT
        STAGE(k + DEPTH, ws);
        cur = (cur == NSLOT - 1) ? 0 : cur + 1;
    }
    asm volatile("s_waitcnt vmcnt(0)" ::: "memory");
    for (int k = Tn - DEPTH; k < Tn; ++k) {
        body(k, cur);
        cur = (cur == NSLOT - 1) ? 0 : cur + 1;
    }

    // ---- epilogue: plain stores (nt stores caused 7x write amp, r3) ----
    const int cbase = g * CG + cslot * 4;
    #pragma unroll
    for (int qq = 0; qq < 4; ++qq) {
        const int q = qt * QT + qsl + 4 * qq;
        float* ob = out + ((size_t)(b * Tn + q) * Cn + cbase) * (Hn * Wn) + off_hw;
        #pragma unroll
        for (int cc = 0; cc < 4; ++cc)
            *(f4*)(ob + cc * (Hn * Wn)) = acc[qq][cc];
    }
#undef STAGE
}

extern "C" void kernel_launch(void* const* d_in, const int* in_sizes, int n_in,
                              void* d_out, int out_size, void* d_ws, size_t ws_size,
                              hipStream_t stream) {
    const float* x    = (const float*)d_in[0];
    const float* attn = (const float*)d_in[1];
    float* out        = (float*)d_out;
    temporal_agg_kernel<<<dim3(Gn * Bn * Hn * 2 * 2), dim3(256), 0, stream>>>(x, attn, out);
}